// Round 4
// baseline (8956.039 us; speedup 1.0000x reference)
//
#include <hip/hip_runtime.h>

#define NEG_SLOPE 0.1f

static inline int cdiv(int a, int b) { return (a + b - 1) / b; }

// ---------------- blocked direct conv + leaky relu ----------------
// Each thread: TCO output channels x TW output columns (TW must be 4).
// blockIdx.z = b * (COUT/TCO) + co_group. Weights for the block's TCO channels
// staged in LDS ([ci][kh][kw][t]; uniform-address reads -> broadcast, ds_read_b128).
// Interior threads load input rows as 3 aligned float4s (wi0 & 3 == ROF, compile-time).
template <int K, int S, int PAD, int CIN, int COUT,
          int HIN, int WIN, int HOUT, int WOUT, int TCO, int TW>
__global__ __launch_bounds__(256, 4) void conv_blk(const float* __restrict__ x,
                                                   const float* __restrict__ w,
                                                   const float* __restrict__ bs,
                                                   float* __restrict__ y) {
    constexpr int SLOTS_W = WOUT / TW;      // thread-slots per output row
    constexpr int NSLOT   = HOUT * SLOTS_W; // thread-slots per (b, co_group) plane
    constexpr int NWT     = TCO * CIN * K * K;
    constexpr int L       = (TW - 1) * S + K;    // input cols needed per row
    constexpr int ROF     = (4 - (PAD & 3)) & 3; // wi0 & 3 for in-range threads
    constexpr int NW4     = (ROF + L + 3) / 4;   // aligned float4 words per row

    __shared__ float wlds[NWT];

    const int zz  = blockIdx.z;
    const int b   = zz / (COUT / TCO);
    const int cob = (zz % (COUT / TCO)) * TCO;

    // stage weights: wlds[((ci*K+kh)*K+kw)*TCO + t] = w[(cob+t)][ci][kh][kw]
    for (int i = threadIdx.x; i < NWT; i += 256) {
        int t    = i % TCO;
        int rest = i / TCO;                 // = ci*K*K + kh*K + kw
        wlds[i] = w[(size_t)(cob + t) * (CIN * K * K) + rest];
    }
    __syncthreads();

    const int slot = blockIdx.x * 256 + threadIdx.x;
    if (slot >= NSLOT) return;

    const int ho = slot / SLOTS_W;
    const int wo = (slot % SLOTS_W) * TW;

    const float* xb = x + (size_t)b * CIN * HIN * WIN;

    float acc[TCO][TW];
#pragma unroll
    for (int t = 0; t < TCO; ++t) {
        float bv = bs[cob + t];
#pragma unroll
        for (int j = 0; j < TW; ++j) acc[t][j] = bv;
    }

    const int hi0 = ho * S - PAD;
    const int wi0 = wo * S - PAD;
    // interior: all K rows in range AND the full 3-word aligned span within the row
    const bool interior = (hi0 >= 0) && (hi0 + K <= HIN) &&
                          (wi0 >= ROF) && (wi0 - ROF + 4 * NW4 <= WIN);

    for (int ci = 0; ci < CIN; ++ci) {
        const float* xc = xb + (size_t)ci * HIN * WIN;
        const float* wc = &wlds[(ci * K * K) * TCO];
#pragma unroll
        for (int kh = 0; kh < K; ++kh) {
            const int hi = hi0 + kh;
            float rb[4 * NW4];
            if (interior) {
                const float4* xr4 = reinterpret_cast<const float4*>(
                    xc + (size_t)hi * WIN + (wi0 - ROF));
#pragma unroll
                for (int u = 0; u < NW4; ++u) {
                    float4 v = xr4[u];
                    rb[4 * u + 0] = v.x; rb[4 * u + 1] = v.y;
                    rb[4 * u + 2] = v.z; rb[4 * u + 3] = v.w;
                }
            } else {
                const bool rowok = (unsigned)hi < (unsigned)HIN;
#pragma unroll
                for (int u = 0; u < L; ++u) {
                    const int wi = wi0 + u;
                    rb[ROF + u] = (rowok && (unsigned)wi < (unsigned)WIN)
                                      ? xc[(size_t)hi * WIN + wi] : 0.0f;
                }
            }
#pragma unroll
            for (int kw = 0; kw < K; ++kw) {
                const float* wg = wc + (kh * K + kw) * TCO;
                float w8[TCO];
#pragma unroll
                for (int t = 0; t < TCO; ++t) w8[t] = wg[t];
#pragma unroll
                for (int j = 0; j < TW; ++j) {
                    const float xv = rb[ROF + kw + j * S];
#pragma unroll
                    for (int t = 0; t < TCO; ++t)
                        acc[t][j] = fmaf(xv, w8[t], acc[t][j]);
                }
            }
        }
    }

    // epilogue: leaky relu + store (wo multiple of TW, WOUT multiple of TW)
#pragma unroll
    for (int t = 0; t < TCO; ++t) {
        float* yr = y + (((size_t)b * COUT + cob + t) * HOUT + ho) * WOUT + wo;
#pragma unroll
        for (int j = 0; j < TW; ++j) {
            const float v = acc[t][j];
            yr[j] = v >= 0.0f ? v : NEG_SLOPE * v;
        }
    }
}

// ---------------- bilinear warp (B=4, H=12, W=24) ----------------
__global__ void warp_kernel(const float* __restrict__ img, const float* __restrict__ flow,
                            float* __restrict__ out, int C) {
    const int H = 12, W = 24, HW = 288;
    int idx = blockIdx.x * blockDim.x + threadIdx.x;
    int total = 4 * C * HW;
    if (idx >= total) return;
    int w = idx % W;
    int h = (idx / W) % H;
    int c = (idx / HW) % C;
    int b = idx / (HW * C);

    float fx = flow[(((size_t)b * 2 + 0) * H + h) * W + w] * 0.625f;
    float fy = flow[(((size_t)b * 2 + 1) * H + h) * W + w] * 0.625f;
    float px = (float)w + fx;
    float py = (float)h + fy;
    float x0f = floorf(px);
    float y0f = floorf(py);
    float wx = px - x0f;
    float wy = py - y0f;
    int x0 = (int)x0f;
    int y0 = (int)y0f;

    const float* ip = img + ((size_t)b * C + c) * HW;
    auto g = [&](int yi, int xi) -> float {
        if (xi < 0 || xi > W - 1 || yi < 0 || yi > H - 1) return 0.0f;
        return ip[yi * W + xi];
    };
    float v = g(y0, x0) * (1.0f - wx) * (1.0f - wy)
            + g(y0, x0 + 1) * wx * (1.0f - wy)
            + g(y0 + 1, x0) * (1.0f - wx) * wy
            + g(y0 + 1, x0 + 1) * wx * wy;
    out[idx] = v;
}

// ---------------- correlation (7x7 disp) + lrelu ----------------
__global__ void corr_lrelu(const float* __restrict__ f1, const float* __restrict__ wp,
                           float* __restrict__ out, int C) {
    const int H = 12, W = 24, HW = 288;
    int idx = blockIdx.x * blockDim.x + threadIdx.x;
    int total = 4 * 49 * HW;
    if (idx >= total) return;
    int w = idx % W;
    int h = (idx / W) % H;
    int d = (idx / HW) % 49;
    int b = idx / (49 * HW);
    int di = d / 7 - 3;
    int dj = d % 7 - 3;
    int h2 = h + di;
    int w2 = w + dj;

    float s = 0.0f;
    if (h2 >= 0 && h2 < H && w2 >= 0 && w2 < W) {
        const float* a = f1 + (size_t)b * C * HW + h * W + w;
        const float* p = wp + (size_t)b * C * HW + h2 * W + w2;
        for (int c = 0; c < C; ++c) s = fmaf(a[(size_t)c * HW], p[(size_t)c * HW], s);
    }
    s /= (float)C;
    s = (s >= 0.0f) ? s : NEG_SLOPE * s;
    out[idx] = s;
}

// ---------------- host ----------------
extern "C" void kernel_launch(void* const* d_in, const int* in_sizes, int n_in,
                              void* d_out, int out_size, void* d_ws, size_t ws_size,
                              hipStream_t stream) {
    const float* img1 = (const float*)d_in[0];
    const float* img2 = (const float*)d_in[1];
    const float* flow = (const float*)d_in[2];
    float* out = (float*)d_out;

    const float* W[10];
    const float* Bs[10];
    for (int l = 0; l < 10; ++l) {
        W[l]  = (const float*)d_in[3 + 2 * l];
        Bs[l] = (const float*)d_in[4 + 2 * l];
    }

    // ws layout identical to proven round-2/3 footprint (47.85M floats = 191.4 MB)
    float* ws = (float*)d_ws;
    size_t off = 0;
    float* bufA = ws + off; off += 37748736;  // 4*32*384*768
    float* bufB = ws + off; off += 9437184;   // 4*32*192*384
    float* f1   = ws + off; off += 221184;    // 4*192*12*24
    float* f2   = ws + off; off += 221184;
    float* wrp  = ws + off; off += 221184;

    auto chain = [&](const float* img, float* fout) {
        // L1: 3->32, 7x7 s1 p3, 384x768
        conv_blk<7,1,3,  3, 32, 384,768, 384,768, 8,4>
            <<<dim3(cdiv(384*(768/4),256),1,4*(32/8)), 256, 0, stream>>>(img,  W[0], Bs[0], bufA);
        // L2: 32->32, 3x3 s2 p1 -> 192x384
        conv_blk<3,2,1, 32, 32, 384,768, 192,384, 8,4>
            <<<dim3(cdiv(192*(384/4),256),1,4*(32/8)), 256, 0, stream>>>(bufA, W[1], Bs[1], bufB);
        // L3: 32->32, s1
        conv_blk<3,1,1, 32, 32, 192,384, 192,384, 8,4>
            <<<dim3(cdiv(192*(384/4),256),1,4*(32/8)), 256, 0, stream>>>(bufB, W[2], Bs[2], bufA);
        // L4: 32->32, s1
        conv_blk<3,1,1, 32, 32, 192,384, 192,384, 8,4>
            <<<dim3(cdiv(192*(384/4),256),1,4*(32/8)), 256, 0, stream>>>(bufA, W[3], Bs[3], bufB);
        // L5: 32->64, s2 -> 96x192
        conv_blk<3,2,1, 32, 64, 192,384,  96,192, 8,4>
            <<<dim3(cdiv(96*(192/4),256),1,4*(64/8)), 256, 0, stream>>>(bufB, W[4], Bs[4], bufA);
        // L6: 64->64, s1
        conv_blk<3,1,1, 64, 64,  96,192,  96,192, 8,4>
            <<<dim3(cdiv(96*(192/4),256),1,4*(64/8)), 256, 0, stream>>>(bufA, W[5], Bs[5], bufB);
        // L7: 64->96, s2 -> 48x96
        conv_blk<3,2,1, 64, 96,  96,192,  48, 96, 8,4>
            <<<dim3(cdiv(48*(96/4),256),1,4*(96/8)), 256, 0, stream>>>(bufB, W[6], Bs[6], bufA);
        // L8: 96->96, s1
        conv_blk<3,1,1, 96, 96,  48, 96,  48, 96, 8,4>
            <<<dim3(cdiv(48*(96/4),256),1,4*(96/8)), 256, 0, stream>>>(bufA, W[7], Bs[7], bufB);
        // L9: 96->128, s2 -> 24x48
        conv_blk<3,2,1, 96,128,  48, 96,  24, 48, 8,4>
            <<<dim3(cdiv(24*(48/4),256),1,4*(128/8)), 256, 0, stream>>>(bufB, W[8], Bs[8], bufA);
        // L10: 128->192, s2 -> 12x24
        conv_blk<3,2,1,128,192,  24, 48,  12, 24, 8,4>
            <<<dim3(cdiv(12*(24/4),256),1,4*(192/8)), 256, 0, stream>>>(bufA, W[9], Bs[9], fout);
    };

    chain(img1, f1);
    chain(img2, f2);

    warp_kernel<<<cdiv(4 * 192 * 288, 256), 256, 0, stream>>>(f2, flow, wrp, 192);
    corr_lrelu<<<cdiv(4 * 49 * 288, 256), 256, 0, stream>>>(f1, wrp, out, 192);
}

// Round 5
// 4426.183 us; speedup vs baseline: 2.0234x; 2.0234x over previous
//
#include <hip/hip_runtime.h>

#define NEG_SLOPE 0.1f

static inline int cdiv(int a, int b) { return (a + b - 1) / b; }

// ---------------- blocked direct conv + leaky relu ----------------
// Each thread: TCO output channels x TW output columns (TW in {4,8}).
// blockIdx.z = b * (COUT/TCO) + co_group. Weights for the block's TCO channels
// staged in LDS ([ci][kh][kw][t]; uniform-address reads -> broadcast ds_read_b128).
// Interior threads load rows as aligned float4 (wi0 & 3 == ROF, compile-time).
// UNROLL_CI=false forces `#pragma unroll 1` on the ci loop (register-pressure
// control for K=7; launch_bounds min-waves caused catastrophic spills in R4).
template <int K, int S, int PAD, int CIN, int COUT,
          int HIN, int WIN, int HOUT, int WOUT, int TCO, int TW, bool UNROLL_CI>
__global__ __launch_bounds__(256) void conv_blk(const float* __restrict__ x,
                                                const float* __restrict__ w,
                                                const float* __restrict__ bs,
                                                float* __restrict__ y) {
    constexpr int SLOTS_W = WOUT / TW;      // thread-slots per output row
    constexpr int NSLOT   = HOUT * SLOTS_W; // thread-slots per (b, co_group) plane
    constexpr int NWT     = TCO * CIN * K * K;
    constexpr int L       = (TW - 1) * S + K;    // input cols needed per row
    constexpr int ROF     = (4 - (PAD & 3)) & 3; // wi0 & 3 for in-range threads
    constexpr int NW4     = (ROF + L + 3) / 4;   // aligned float4 words per row

    __shared__ float wlds[NWT];

    const int zz  = blockIdx.z;
    const int b   = zz / (COUT / TCO);
    const int cob = (zz % (COUT / TCO)) * TCO;

    // stage weights: wlds[((ci*K+kh)*K+kw)*TCO + t] = w[(cob+t)][ci][kh][kw]
    for (int i = threadIdx.x; i < NWT; i += 256) {
        int t    = i % TCO;
        int rest = i / TCO;                 // = ci*K*K + kh*K + kw
        wlds[i] = w[(size_t)(cob + t) * (CIN * K * K) + rest];
    }
    __syncthreads();

    const int slot = blockIdx.x * 256 + threadIdx.x;
    if (slot >= NSLOT) return;

    const int ho = slot / SLOTS_W;
    const int wo = (slot % SLOTS_W) * TW;

    const float* xb = x + (size_t)b * CIN * HIN * WIN;

    float acc[TCO][TW];
#pragma unroll
    for (int t = 0; t < TCO; ++t) {
        float bv = bs[cob + t];
#pragma unroll
        for (int j = 0; j < TW; ++j) acc[t][j] = bv;
    }

    const int hi0 = ho * S - PAD;
    const int wi0 = wo * S - PAD;
    const bool interior = (hi0 >= 0) && (hi0 + K <= HIN) &&
                          (wi0 >= ROF) && (wi0 - ROF + 4 * NW4 <= WIN);

    auto ci_body = [&](int ci) {
        const float* xc = xb + (size_t)ci * HIN * WIN;
        const float* wc = &wlds[(ci * K * K) * TCO];
#pragma unroll
        for (int kh = 0; kh < K; ++kh) {
            const int hi = hi0 + kh;
            float rb[4 * NW4];
            if (interior) {
                const float4* xr4 = reinterpret_cast<const float4*>(
                    xc + (size_t)hi * WIN + (wi0 - ROF));
#pragma unroll
                for (int u = 0; u < NW4; ++u) {
                    float4 v = xr4[u];
                    rb[4 * u + 0] = v.x; rb[4 * u + 1] = v.y;
                    rb[4 * u + 2] = v.z; rb[4 * u + 3] = v.w;
                }
            } else {
                const bool rowok = (unsigned)hi < (unsigned)HIN;
#pragma unroll
                for (int u = 0; u < L; ++u) {
                    const int wi = wi0 + u;
                    rb[ROF + u] = (rowok && (unsigned)wi < (unsigned)WIN)
                                      ? xc[(size_t)hi * WIN + wi] : 0.0f;
                }
            }
#pragma unroll
            for (int kw = 0; kw < K; ++kw) {
                const float* wg = wc + (kh * K + kw) * TCO;
                float w8[TCO];
#pragma unroll
                for (int t = 0; t < TCO; ++t) w8[t] = wg[t];
#pragma unroll
                for (int j = 0; j < TW; ++j) {
                    const float xv = rb[ROF + kw + j * S];
#pragma unroll
                    for (int t = 0; t < TCO; ++t)
                        acc[t][j] = fmaf(xv, w8[t], acc[t][j]);
                }
            }
        }
    };

    if constexpr (UNROLL_CI) {
        for (int ci = 0; ci < CIN; ++ci) ci_body(ci);
    } else {
#pragma unroll 1
        for (int ci = 0; ci < CIN; ++ci) ci_body(ci);
    }

    // epilogue: leaky relu + store (wo multiple of TW, WOUT multiple of TW)
#pragma unroll
    for (int t = 0; t < TCO; ++t) {
        float* yr = y + (((size_t)b * COUT + cob + t) * HOUT + ho) * WOUT + wo;
#pragma unroll
        for (int j = 0; j < TW; ++j) {
            const float v = acc[t][j];
            yr[j] = v >= 0.0f ? v : NEG_SLOPE * v;
        }
    }
}

// ---------------- bilinear warp (B=4, H=12, W=24) ----------------
__global__ void warp_kernel(const float* __restrict__ img, const float* __restrict__ flow,
                            float* __restrict__ out, int C) {
    const int H = 12, W = 24, HW = 288;
    int idx = blockIdx.x * blockDim.x + threadIdx.x;
    int total = 4 * C * HW;
    if (idx >= total) return;
    int w = idx % W;
    int h = (idx / W) % H;
    int c = (idx / HW) % C;
    int b = idx / (HW * C);

    float fx = flow[(((size_t)b * 2 + 0) * H + h) * W + w] * 0.625f;
    float fy = flow[(((size_t)b * 2 + 1) * H + h) * W + w] * 0.625f;
    float px = (float)w + fx;
    float py = (float)h + fy;
    float x0f = floorf(px);
    float y0f = floorf(py);
    float wx = px - x0f;
    float wy = py - y0f;
    int x0 = (int)x0f;
    int y0 = (int)y0f;

    const float* ip = img + ((size_t)b * C + c) * HW;
    auto g = [&](int yi, int xi) -> float {
        if (xi < 0 || xi > W - 1 || yi < 0 || yi > H - 1) return 0.0f;
        return ip[yi * W + xi];
    };
    float v = g(y0, x0) * (1.0f - wx) * (1.0f - wy)
            + g(y0, x0 + 1) * wx * (1.0f - wy)
            + g(y0 + 1, x0) * (1.0f - wx) * wy
            + g(y0 + 1, x0 + 1) * wx * wy;
    out[idx] = v;
}

// ---------------- correlation (7x7 disp) + lrelu ----------------
__global__ void corr_lrelu(const float* __restrict__ f1, const float* __restrict__ wp,
                           float* __restrict__ out, int C) {
    const int H = 12, W = 24, HW = 288;
    int idx = blockIdx.x * blockDim.x + threadIdx.x;
    int total = 4 * 49 * HW;
    if (idx >= total) return;
    int w = idx % W;
    int h = (idx / W) % H;
    int d = (idx / HW) % 49;
    int b = idx / (49 * HW);
    int di = d / 7 - 3;
    int dj = d % 7 - 3;
    int h2 = h + di;
    int w2 = w + dj;

    float s = 0.0f;
    if (h2 >= 0 && h2 < H && w2 >= 0 && w2 < W) {
        const float* a = f1 + (size_t)b * C * HW + h * W + w;
        const float* p = wp + (size_t)b * C * HW + h2 * W + w2;
        for (int c = 0; c < C; ++c) s = fmaf(a[(size_t)c * HW], p[(size_t)c * HW], s);
    }
    s /= (float)C;
    s = (s >= 0.0f) ? s : NEG_SLOPE * s;
    out[idx] = s;
}

// ---------------- host ----------------
extern "C" void kernel_launch(void* const* d_in, const int* in_sizes, int n_in,
                              void* d_out, int out_size, void* d_ws, size_t ws_size,
                              hipStream_t stream) {
    const float* img1 = (const float*)d_in[0];
    const float* img2 = (const float*)d_in[1];
    const float* flow = (const float*)d_in[2];
    float* out = (float*)d_out;

    const float* W[10];
    const float* Bs[10];
    for (int l = 0; l < 10; ++l) {
        W[l]  = (const float*)d_in[3 + 2 * l];
        Bs[l] = (const float*)d_in[4 + 2 * l];
    }

    // ws layout identical to proven round-2/3 footprint (47.85M floats = 191.4 MB)
    float* ws = (float*)d_ws;
    size_t off = 0;
    float* bufA = ws + off; off += 37748736;  // 4*32*384*768
    float* bufB = ws + off; off += 9437184;   // 4*32*192*384
    float* f1   = ws + off; off += 221184;    // 4*192*12*24
    float* f2   = ws + off; off += 221184;
    float* wrp  = ws + off; off += 221184;

    auto chain = [&](const float* img, float* fout) {
        // L1: 3->32, 7x7 s1 p3, 384x768. ci loop NOT unrolled (R3: full unroll -> 256 VGPR + spills)
        conv_blk<7,1,3,  3, 32, 384,768, 384,768, 8,4,false>
            <<<dim3(cdiv(384*(768/4),256),1,4*(32/8)), 256, 0, stream>>>(img,  W[0], Bs[0], bufA);
        // L2: 32->32, 3x3 s2 p1 -> 192x384, TW=8 (big layer: more ILP per wave)
        conv_blk<3,2,1, 32, 32, 384,768, 192,384, 8,8,true>
            <<<dim3(cdiv(192*(384/8),256),1,4*(32/8)), 256, 0, stream>>>(bufA, W[1], Bs[1], bufB);
        // L3: 32->32, s1, TW=8
        conv_blk<3,1,1, 32, 32, 192,384, 192,384, 8,8,true>
            <<<dim3(cdiv(192*(384/8),256),1,4*(32/8)), 256, 0, stream>>>(bufB, W[2], Bs[2], bufA);
        // L4: 32->32, s1, TW=8
        conv_blk<3,1,1, 32, 32, 192,384, 192,384, 8,8,true>
            <<<dim3(cdiv(192*(384/8),256),1,4*(32/8)), 256, 0, stream>>>(bufA, W[3], Bs[3], bufB);
        // L5: 32->64, s2 -> 96x192
        conv_blk<3,2,1, 32, 64, 192,384,  96,192, 8,4,true>
            <<<dim3(cdiv(96*(192/4),256),1,4*(64/8)), 256, 0, stream>>>(bufB, W[4], Bs[4], bufA);
        // L6: 64->64, s1
        conv_blk<3,1,1, 64, 64,  96,192,  96,192, 8,4,true>
            <<<dim3(cdiv(96*(192/4),256),1,4*(64/8)), 256, 0, stream>>>(bufA, W[5], Bs[5], bufB);
        // L7: 64->96, s2 -> 48x96
        conv_blk<3,2,1, 64, 96,  96,192,  48, 96, 8,4,true>
            <<<dim3(cdiv(48*(96/4),256),1,4*(96/8)), 256, 0, stream>>>(bufB, W[6], Bs[6], bufA);
        // L8: 96->96, s1
        conv_blk<3,1,1, 96, 96,  48, 96,  48, 96, 8,4,true>
            <<<dim3(cdiv(48*(96/4),256),1,4*(96/8)), 256, 0, stream>>>(bufA, W[7], Bs[7], bufB);
        // L9: 96->128, s2 -> 24x48
        conv_blk<3,2,1, 96,128,  48, 96,  24, 48, 8,4,true>
            <<<dim3(cdiv(24*(48/4),256),1,4*(128/8)), 256, 0, stream>>>(bufB, W[8], Bs[8], bufA);
        // L10: 128->192, s2 -> 12x24
        conv_blk<3,2,1,128,192,  24, 48,  12, 24, 8,4,true>
            <<<dim3(cdiv(12*(24/4),256),1,4*(192/8)), 256, 0, stream>>>(bufA, W[9], Bs[9], fout);
    };

    chain(img1, f1);
    chain(img2, f2);

    warp_kernel<<<cdiv(4 * 192 * 288, 256), 256, 0, stream>>>(f2, flow, wrp, 192);
    corr_lrelu<<<cdiv(4 * 49 * 288, 256), 256, 0, stream>>>(f1, wrp, out, 192);
}

// Round 6
// 3963.445 us; speedup vs baseline: 2.2597x; 1.1168x over previous
//
#include <hip/hip_runtime.h>

#define NEG_SLOPE 0.1f

static inline int cdiv(int a, int b) { return (a + b - 1) / b; }

// ---------------- L1 special: 7x7, CIN=3, stride1 ----------------
// kh-outer loop NOT unrolled: only one kh-row x 3 ci live (36 regs) ->
// no spills (R3/R5 L1 hit 256 VGPR + scratch via kh-unroll row buffers).
// Per kh iter: 9 aligned float4 loads, 672 FMAs.
template <int COUT, int H, int W>
__global__ __launch_bounds__(256) void conv7x7(const float* __restrict__ x,
                                               const float* __restrict__ w,
                                               const float* __restrict__ bs,
                                               float* __restrict__ y) {
    constexpr int CIN = 3, K = 7, PAD = 3, TCO = 8, TW = 4;
    constexpr int SLOTS_W = W / TW;
    constexpr int NSLOT   = H * SLOTS_W;
    constexpr int NWT     = TCO * CIN * K * K;     // 1176
    constexpr int L       = TW - 1 + K;            // 10
    constexpr int ROF     = (4 - (PAD & 3)) & 3;   // 1
    constexpr int NW4     = (ROF + L + 3) / 4;     // 3

    __shared__ float wlds[NWT];

    const int zz  = blockIdx.z;
    const int b   = zz / (COUT / TCO);
    const int cob = (zz % (COUT / TCO)) * TCO;

    for (int i = threadIdx.x; i < NWT; i += 256) {
        int t = i % TCO, rest = i / TCO;
        wlds[i] = w[(size_t)(cob + t) * (CIN * K * K) + rest];
    }
    __syncthreads();

    const int slot = blockIdx.x * 256 + threadIdx.x;
    if (slot >= NSLOT) return;
    const int ho = slot / SLOTS_W;
    const int wo = (slot % SLOTS_W) * TW;

    const float* xb = x + (size_t)b * CIN * H * W;

    float acc[TCO][TW];
#pragma unroll
    for (int t = 0; t < TCO; ++t) {
        float bv = bs[cob + t];
#pragma unroll
        for (int j = 0; j < TW; ++j) acc[t][j] = bv;
    }

    const int hi0 = ho - PAD;
    const int wi0 = wo - PAD;
    const bool interior = (hi0 >= 0) && (hi0 + K <= H) &&
                          (wi0 >= ROF) && (wi0 - ROF + 4 * NW4 <= W);

#pragma unroll 1
    for (int kh = 0; kh < K; ++kh) {
        const int hi = hi0 + kh;
        float rb[CIN][4 * NW4];
        const bool rowok = (unsigned)hi < (unsigned)H;
#pragma unroll
        for (int ci = 0; ci < CIN; ++ci) {
            const float* xc = xb + (size_t)ci * H * W;
            if (interior) {
                const float4* xr4 = reinterpret_cast<const float4*>(
                    xc + (size_t)hi * W + (wi0 - ROF));
#pragma unroll
                for (int u = 0; u < NW4; ++u) {
                    float4 v = xr4[u];
                    rb[ci][4 * u + 0] = v.x; rb[ci][4 * u + 1] = v.y;
                    rb[ci][4 * u + 2] = v.z; rb[ci][4 * u + 3] = v.w;
                }
            } else {
#pragma unroll
                for (int u = 0; u < L; ++u) {
                    const int wi = wi0 + u;
                    rb[ci][ROF + u] = (rowok && (unsigned)wi < (unsigned)W)
                                          ? xc[(size_t)hi * W + wi] : 0.0f;
                }
            }
        }
#pragma unroll
        for (int ci = 0; ci < CIN; ++ci) {
            const float* wc = &wlds[((ci * K + kh) * K) * TCO];
#pragma unroll
            for (int kw = 0; kw < K; ++kw) {
                const float* wg = wc + kw * TCO;
                float w8[TCO];
#pragma unroll
                for (int t = 0; t < TCO; ++t) w8[t] = wg[t];
#pragma unroll
                for (int j = 0; j < TW; ++j) {
                    const float xv = rb[ci][ROF + kw + j];
#pragma unroll
                    for (int t = 0; t < TCO; ++t)
                        acc[t][j] = fmaf(xv, w8[t], acc[t][j]);
                }
            }
        }
    }

#pragma unroll
    for (int t = 0; t < TCO; ++t) {
        float* yr = y + (((size_t)b * COUT + cob + t) * H + ho) * W + wo;
#pragma unroll
        for (int j = 0; j < TW; ++j) {
            const float v = acc[t][j];
            yr[j] = v >= 0.0f ? v : NEG_SLOPE * v;
        }
    }
}

// ---------------- 3x3 conv, TCO=8 x TW=4, ci ping-pong prefetch ----------------
// R3 config (72 VGPR, spill-free) + software pipeline: next ci's 3 rows load
// while current ci's 288 FMAs issue (~576 cyc latency cover). CIN even.
template <int S, int PAD, int CIN, int COUT, int HIN, int WIN, int HOUT, int WOUT>
__global__ __launch_bounds__(256) void conv3x3(const float* __restrict__ x,
                                               const float* __restrict__ w,
                                               const float* __restrict__ bs,
                                               float* __restrict__ y) {
    constexpr int K = 3, TCO = 8, TW = 4;
    static_assert(CIN % 2 == 0, "ping-pong needs even CIN");
    constexpr int SLOTS_W = WOUT / TW;
    constexpr int NSLOT   = HOUT * SLOTS_W;
    constexpr int NWT     = TCO * CIN * K * K;
    constexpr int L       = (TW - 1) * S + K;
    constexpr int ROF     = (4 - (PAD & 3)) & 3;
    constexpr int NW4     = (ROF + L + 3) / 4;     // 3 for all configs used

    __shared__ float wlds[NWT];

    const int zz  = blockIdx.z;
    const int b   = zz / (COUT / TCO);
    const int cob = (zz % (COUT / TCO)) * TCO;

    for (int i = threadIdx.x; i < NWT; i += 256) {
        int t = i % TCO, rest = i / TCO;
        wlds[i] = w[(size_t)(cob + t) * (CIN * K * K) + rest];
    }
    __syncthreads();

    const int slot = blockIdx.x * 256 + threadIdx.x;
    if (slot >= NSLOT) return;
    const int ho = slot / SLOTS_W;
    const int wo = (slot % SLOTS_W) * TW;

    const float* xb = x + (size_t)b * CIN * HIN * WIN;

    float acc[TCO][TW];
#pragma unroll
    for (int t = 0; t < TCO; ++t) {
        float bv = bs[cob + t];
#pragma unroll
        for (int j = 0; j < TW; ++j) acc[t][j] = bv;
    }

    const int hi0 = ho * S - PAD;
    const int wi0 = wo * S - PAD;
    const bool interior = (hi0 >= 0) && (hi0 + K <= HIN) &&
                          (wi0 >= ROF) && (wi0 - ROF + 4 * NW4 <= WIN);

    auto load_ci = [&](int ci, float (&rb)[K][4 * NW4]) {
        const float* xc = xb + (size_t)ci * HIN * WIN;
#pragma unroll
        for (int kh = 0; kh < K; ++kh) {
            const int hi = hi0 + kh;
            if (interior) {
                const float4* xr4 = reinterpret_cast<const float4*>(
                    xc + (size_t)hi * WIN + (wi0 - ROF));
#pragma unroll
                for (int u = 0; u < NW4; ++u) {
                    float4 v = xr4[u];
                    rb[kh][4 * u + 0] = v.x; rb[kh][4 * u + 1] = v.y;
                    rb[kh][4 * u + 2] = v.z; rb[kh][4 * u + 3] = v.w;
                }
            } else {
                const bool rowok = (unsigned)hi < (unsigned)HIN;
#pragma unroll
                for (int u = 0; u < L; ++u) {
                    const int wi = wi0 + u;
                    rb[kh][ROF + u] = (rowok && (unsigned)wi < (unsigned)WIN)
                                          ? xc[(size_t)hi * WIN + wi] : 0.0f;
                }
            }
        }
    };

    auto fma_ci = [&](int ci, const float (&rb)[K][4 * NW4]) {
        const float* wc = &wlds[(ci * K * K) * TCO];
#pragma unroll
        for (int kh = 0; kh < K; ++kh) {
#pragma unroll
            for (int kw = 0; kw < K; ++kw) {
                const float* wg = wc + (kh * K + kw) * TCO;
                float w8[TCO];
#pragma unroll
                for (int t = 0; t < TCO; ++t) w8[t] = wg[t];
#pragma unroll
                for (int j = 0; j < TW; ++j) {
                    const float xv = rb[kh][ROF + kw + j * S];
#pragma unroll
                    for (int t = 0; t < TCO; ++t)
                        acc[t][j] = fmaf(xv, w8[t], acc[t][j]);
                }
            }
        }
    };

    float rbA[K][4 * NW4], rbB[K][4 * NW4];
    load_ci(0, rbA);
#pragma unroll 1
    for (int ci = 0; ci < CIN; ci += 2) {
        load_ci(ci + 1, rbB);
        fma_ci(ci, rbA);
        if (ci + 2 < CIN) load_ci(ci + 2, rbA);
        fma_ci(ci + 1, rbB);
    }

#pragma unroll
    for (int t = 0; t < TCO; ++t) {
        float* yr = y + (((size_t)b * COUT + cob + t) * HOUT + ho) * WOUT + wo;
#pragma unroll
        for (int j = 0; j < TW; ++j) {
            const float v = acc[t][j];
            yr[j] = v >= 0.0f ? v : NEG_SLOPE * v;
        }
    }
}

// ---------------- bilinear warp (B=4, H=12, W=24) ----------------
__global__ void warp_kernel(const float* __restrict__ img, const float* __restrict__ flow,
                            float* __restrict__ out, int C) {
    const int H = 12, W = 24, HW = 288;
    int idx = blockIdx.x * blockDim.x + threadIdx.x;
    int total = 4 * C * HW;
    if (idx >= total) return;
    int w = idx % W;
    int h = (idx / W) % H;
    int c = (idx / HW) % C;
    int b = idx / (HW * C);

    float fx = flow[(((size_t)b * 2 + 0) * H + h) * W + w] * 0.625f;
    float fy = flow[(((size_t)b * 2 + 1) * H + h) * W + w] * 0.625f;
    float px = (float)w + fx;
    float py = (float)h + fy;
    float x0f = floorf(px);
    float y0f = floorf(py);
    float wx = px - x0f;
    float wy = py - y0f;
    int x0 = (int)x0f;
    int y0 = (int)y0f;

    const float* ip = img + ((size_t)b * C + c) * HW;
    auto g = [&](int yi, int xi) -> float {
        if (xi < 0 || xi > W - 1 || yi < 0 || yi > H - 1) return 0.0f;
        return ip[yi * W + xi];
    };
    float v = g(y0, x0) * (1.0f - wx) * (1.0f - wy)
            + g(y0, x0 + 1) * wx * (1.0f - wy)
            + g(y0 + 1, x0) * (1.0f - wx) * wy
            + g(y0 + 1, x0 + 1) * wx * wy;
    out[idx] = v;
}

// ---------------- correlation (7x7 disp) + lrelu ----------------
__global__ void corr_lrelu(const float* __restrict__ f1, const float* __restrict__ wp,
                           float* __restrict__ out, int C) {
    const int H = 12, W = 24, HW = 288;
    int idx = blockIdx.x * blockDim.x + threadIdx.x;
    int total = 4 * 49 * HW;
    if (idx >= total) return;
    int w = idx % W;
    int h = (idx / W) % H;
    int d = (idx / HW) % 49;
    int b = idx / (49 * HW);
    int di = d / 7 - 3;
    int dj = d % 7 - 3;
    int h2 = h + di;
    int w2 = w + dj;

    float s = 0.0f;
    if (h2 >= 0 && h2 < H && w2 >= 0 && w2 < W) {
        const float* a = f1 + (size_t)b * C * HW + h * W + w;
        const float* p = wp + (size_t)b * C * HW + h2 * W + w2;
        for (int c = 0; c < C; ++c) s = fmaf(a[(size_t)c * HW], p[(size_t)c * HW], s);
    }
    s /= (float)C;
    s = (s >= 0.0f) ? s : NEG_SLOPE * s;
    out[idx] = s;
}

// ---------------- host ----------------
extern "C" void kernel_launch(void* const* d_in, const int* in_sizes, int n_in,
                              void* d_out, int out_size, void* d_ws, size_t ws_size,
                              hipStream_t stream) {
    const float* img1 = (const float*)d_in[0];
    const float* img2 = (const float*)d_in[1];
    const float* flow = (const float*)d_in[2];
    float* out = (float*)d_out;

    const float* W[10];
    const float* Bs[10];
    for (int l = 0; l < 10; ++l) {
        W[l]  = (const float*)d_in[3 + 2 * l];
        Bs[l] = (const float*)d_in[4 + 2 * l];
    }

    // ws layout identical to proven footprint (47.85M floats = 191.4 MB)
    float* ws = (float*)d_ws;
    size_t off = 0;
    float* bufA = ws + off; off += 37748736;  // 4*32*384*768
    float* bufB = ws + off; off += 9437184;   // 4*32*192*384
    float* f1   = ws + off; off += 221184;    // 4*192*12*24
    float* f2   = ws + off; off += 221184;
    float* wrp  = ws + off; off += 221184;

    auto chain = [&](const float* img, float* fout) {
        // L1: 3->32, 7x7 s1 p3, 384x768 (kh-outer, unroll 1 -> no spill)
        conv7x7<32, 384, 768>
            <<<dim3(cdiv(384*(768/4),256),1,4*(32/8)), 256, 0, stream>>>(img,  W[0], Bs[0], bufA);
        // L2: 32->32, 3x3 s2 p1 -> 192x384
        conv3x3<2,1, 32, 32, 384,768, 192,384>
            <<<dim3(cdiv(192*(384/4),256),1,4*(32/8)), 256, 0, stream>>>(bufA, W[1], Bs[1], bufB);
        // L3: 32->32, s1
        conv3x3<1,1, 32, 32, 192,384, 192,384>
            <<<dim3(cdiv(192*(384/4),256),1,4*(32/8)), 256, 0, stream>>>(bufB, W[2], Bs[2], bufA);
        // L4: 32->32, s1
        conv3x3<1,1, 32, 32, 192,384, 192,384>
            <<<dim3(cdiv(192*(384/4),256),1,4*(32/8)), 256, 0, stream>>>(bufA, W[3], Bs[3], bufB);
        // L5: 32->64, s2 -> 96x192
        conv3x3<2,1, 32, 64, 192,384,  96,192>
            <<<dim3(cdiv(96*(192/4),256),1,4*(64/8)), 256, 0, stream>>>(bufB, W[4], Bs[4], bufA);
        // L6: 64->64, s1
        conv3x3<1,1, 64, 64,  96,192,  96,192>
            <<<dim3(cdiv(96*(192/4),256),1,4*(64/8)), 256, 0, stream>>>(bufA, W[5], Bs[5], bufB);
        // L7: 64->96, s2 -> 48x96
        conv3x3<2,1, 64, 96,  96,192,  48, 96>
            <<<dim3(cdiv(48*(96/4),256),1,4*(96/8)), 256, 0, stream>>>(bufB, W[6], Bs[6], bufA);
        // L8: 96->96, s1
        conv3x3<1,1, 96, 96,  48, 96,  48, 96>
            <<<dim3(cdiv(48*(96/4),256),1,4*(96/8)), 256, 0, stream>>>(bufA, W[7], Bs[7], bufB);
        // L9: 96->128, s2 -> 24x48
        conv3x3<2,1, 96,128,  48, 96,  24, 48>
            <<<dim3(cdiv(24*(48/4),256),1,4*(128/8)), 256, 0, stream>>>(bufB, W[8], Bs[8], bufA);
        // L10: 128->192, s2 -> 12x24
        conv3x3<2,1,128,192,  24, 48,  12, 24>
            <<<dim3(cdiv(12*(24/4),256),1,4*(192/8)), 256, 0, stream>>>(bufA, W[9], Bs[9], fout);
    };

    chain(img1, f1);
    chain(img2, f2);

    warp_kernel<<<cdiv(4 * 192 * 288, 256), 256, 0, stream>>>(f2, flow, wrp, 192);
    corr_lrelu<<<cdiv(4 * 49 * 288, 256), 256, 0, stream>>>(f1, wrp, out, 192);
}

// Round 7
// 3121.740 us; speedup vs baseline: 2.8689x; 1.2696x over previous
//
#include <hip/hip_runtime.h>

#define NEG_SLOPE 0.1f

static inline int cdiv(int a, int b) { return (a + b - 1) / b; }

// ---------------- L1 special: 7x7, CIN=3, stride1 (R6 version — measured win) ----------------
// kh-outer loop NOT unrolled: only one kh-row x 3 ci live -> no spills.
// Per kh iter: 9 aligned float4 loads, 672 FMAs.
template <int COUT, int H, int W>
__global__ __launch_bounds__(256) void conv7x7(const float* __restrict__ x,
                                               const float* __restrict__ w,
                                               const float* __restrict__ bs,
                                               float* __restrict__ y) {
    constexpr int CIN = 3, K = 7, PAD = 3, TCO = 8, TW = 4;
    constexpr int SLOTS_W = W / TW;
    constexpr int NSLOT   = H * SLOTS_W;
    constexpr int NWT     = TCO * CIN * K * K;     // 1176
    constexpr int L       = TW - 1 + K;            // 10
    constexpr int ROF     = (4 - (PAD & 3)) & 3;   // 1
    constexpr int NW4     = (ROF + L + 3) / 4;     // 3

    __shared__ float wlds[NWT];

    const int zz  = blockIdx.z;
    const int b   = zz / (COUT / TCO);
    const int cob = (zz % (COUT / TCO)) * TCO;

    for (int i = threadIdx.x; i < NWT; i += 256) {
        int t = i % TCO, rest = i / TCO;
        wlds[i] = w[(size_t)(cob + t) * (CIN * K * K) + rest];
    }
    __syncthreads();

    const int slot = blockIdx.x * 256 + threadIdx.x;
    if (slot >= NSLOT) return;
    const int ho = slot / SLOTS_W;
    const int wo = (slot % SLOTS_W) * TW;

    const float* xb = x + (size_t)b * CIN * H * W;

    float acc[TCO][TW];
#pragma unroll
    for (int t = 0; t < TCO; ++t) {
        float bv = bs[cob + t];
#pragma unroll
        for (int j = 0; j < TW; ++j) acc[t][j] = bv;
    }

    const int hi0 = ho - PAD;
    const int wi0 = wo - PAD;
    const bool interior = (hi0 >= 0) && (hi0 + K <= H) &&
                          (wi0 >= ROF) && (wi0 - ROF + 4 * NW4 <= W);

#pragma unroll 1
    for (int kh = 0; kh < K; ++kh) {
        const int hi = hi0 + kh;
        float rb[CIN][4 * NW4];
        const bool rowok = (unsigned)hi < (unsigned)H;
#pragma unroll
        for (int ci = 0; ci < CIN; ++ci) {
            const float* xc = xb + (size_t)ci * H * W;
            if (interior) {
                const float4* xr4 = reinterpret_cast<const float4*>(
                    xc + (size_t)hi * W + (wi0 - ROF));
#pragma unroll
                for (int u = 0; u < NW4; ++u) {
                    float4 v = xr4[u];
                    rb[ci][4 * u + 0] = v.x; rb[ci][4 * u + 1] = v.y;
                    rb[ci][4 * u + 2] = v.z; rb[ci][4 * u + 3] = v.w;
                }
            } else {
#pragma unroll
                for (int u = 0; u < L; ++u) {
                    const int wi = wi0 + u;
                    rb[ci][ROF + u] = (rowok && (unsigned)wi < (unsigned)W)
                                          ? xc[(size_t)hi * W + wi] : 0.0f;
                }
            }
        }
#pragma unroll
        for (int ci = 0; ci < CIN; ++ci) {
            const float* wc = &wlds[((ci * K + kh) * K) * TCO];
#pragma unroll
            for (int kw = 0; kw < K; ++kw) {
                const float* wg = wc + kw * TCO;
                float w8[TCO];
#pragma unroll
                for (int t = 0; t < TCO; ++t) w8[t] = wg[t];
#pragma unroll
                for (int j = 0; j < TW; ++j) {
                    const float xv = rb[ci][ROF + kw + j];
#pragma unroll
                    for (int t = 0; t < TCO; ++t)
                        acc[t][j] = fmaf(xv, w8[t], acc[t][j]);
                }
            }
        }
    }

#pragma unroll
    for (int t = 0; t < TCO; ++t) {
        float* yr = y + (((size_t)b * COUT + cob + t) * H + ho) * W + wo;
#pragma unroll
        for (int j = 0; j < TW; ++j) {
            const float v = acc[t][j];
            yr[j] = v >= 0.0f ? v : NEG_SLOPE * v;
        }
    }
}

// ---------------- blocked direct conv + leaky relu (R3 version — 72 VGPR, measured best) ----------------
// Each thread: TCO output channels x TW=4 output columns. Plain ci loop, no
// prefetch ping-pong (R6 measured: +40 VGPR, TLP loss, net regression).
template <int K, int S, int PAD, int CIN, int COUT,
          int HIN, int WIN, int HOUT, int WOUT, int TCO, int TW>
__global__ __launch_bounds__(256) void conv_blk(const float* __restrict__ x,
                                                const float* __restrict__ w,
                                                const float* __restrict__ bs,
                                                float* __restrict__ y) {
    constexpr int SLOTS_W = WOUT / TW;
    constexpr int NSLOT   = HOUT * SLOTS_W;
    constexpr int NWT     = TCO * CIN * K * K;
    constexpr int L       = (TW - 1) * S + K;
    constexpr int ROF     = (4 - (PAD & 3)) & 3;
    constexpr int NW4     = (ROF + L + 3) / 4;

    __shared__ float wlds[NWT];

    const int zz  = blockIdx.z;
    const int b   = zz / (COUT / TCO);
    const int cob = (zz % (COUT / TCO)) * TCO;

    for (int i = threadIdx.x; i < NWT; i += 256) {
        int t    = i % TCO;
        int rest = i / TCO;
        wlds[i] = w[(size_t)(cob + t) * (CIN * K * K) + rest];
    }
    __syncthreads();

    const int slot = blockIdx.x * 256 + threadIdx.x;
    if (slot >= NSLOT) return;

    const int ho = slot / SLOTS_W;
    const int wo = (slot % SLOTS_W) * TW;

    const float* xb = x + (size_t)b * CIN * HIN * WIN;

    float acc[TCO][TW];
#pragma unroll
    for (int t = 0; t < TCO; ++t) {
        float bv = bs[cob + t];
#pragma unroll
        for (int j = 0; j < TW; ++j) acc[t][j] = bv;
    }

    const int hi0 = ho * S - PAD;
    const int wi0 = wo * S - PAD;
    const bool interior = (hi0 >= 0) && (hi0 + K <= HIN) &&
                          (wi0 >= ROF) && (wi0 - ROF + 4 * NW4 <= WIN);

    for (int ci = 0; ci < CIN; ++ci) {
        const float* xc = xb + (size_t)ci * HIN * WIN;
        const float* wc = &wlds[(ci * K * K) * TCO];
#pragma unroll
        for (int kh = 0; kh < K; ++kh) {
            const int hi = hi0 + kh;
            float rb[4 * NW4];
            if (interior) {
                const float4* xr4 = reinterpret_cast<const float4*>(
                    xc + (size_t)hi * WIN + (wi0 - ROF));
#pragma unroll
                for (int u = 0; u < NW4; ++u) {
                    float4 v = xr4[u];
                    rb[4 * u + 0] = v.x; rb[4 * u + 1] = v.y;
                    rb[4 * u + 2] = v.z; rb[4 * u + 3] = v.w;
                }
            } else {
                const bool rowok = (unsigned)hi < (unsigned)HIN;
#pragma unroll
                for (int u = 0; u < L; ++u) {
                    const int wi = wi0 + u;
                    rb[ROF + u] = (rowok && (unsigned)wi < (unsigned)WIN)
                                      ? xc[(size_t)hi * WIN + wi] : 0.0f;
                }
            }
#pragma unroll
            for (int kw = 0; kw < K; ++kw) {
                const float* wg = wc + (kh * K + kw) * TCO;
                float w8[TCO];
#pragma unroll
                for (int t = 0; t < TCO; ++t) w8[t] = wg[t];
#pragma unroll
                for (int j = 0; j < TW; ++j) {
                    const float xv = rb[ROF + kw + j * S];
#pragma unroll
                    for (int t = 0; t < TCO; ++t)
                        acc[t][j] = fmaf(xv, w8[t], acc[t][j]);
                }
            }
        }
    }

#pragma unroll
    for (int t = 0; t < TCO; ++t) {
        float* yr = y + (((size_t)b * COUT + cob + t) * HOUT + ho) * WOUT + wo;
#pragma unroll
        for (int j = 0; j < TW; ++j) {
            const float v = acc[t][j];
            yr[j] = v >= 0.0f ? v : NEG_SLOPE * v;
        }
    }
}

// ---------------- bilinear warp (B=4, H=12, W=24) ----------------
__global__ void warp_kernel(const float* __restrict__ img, const float* __restrict__ flow,
                            float* __restrict__ out, int C) {
    const int H = 12, W = 24, HW = 288;
    int idx = blockIdx.x * blockDim.x + threadIdx.x;
    int total = 4 * C * HW;
    if (idx >= total) return;
    int w = idx % W;
    int h = (idx / W) % H;
    int c = (idx / HW) % C;
    int b = idx / (HW * C);

    float fx = flow[(((size_t)b * 2 + 0) * H + h) * W + w] * 0.625f;
    float fy = flow[(((size_t)b * 2 + 1) * H + h) * W + w] * 0.625f;
    float px = (float)w + fx;
    float py = (float)h + fy;
    float x0f = floorf(px);
    float y0f = floorf(py);
    float wx = px - x0f;
    float wy = py - y0f;
    int x0 = (int)x0f;
    int y0 = (int)y0f;

    const float* ip = img + ((size_t)b * C + c) * HW;
    auto g = [&](int yi, int xi) -> float {
        if (xi < 0 || xi > W - 1 || yi < 0 || yi > H - 1) return 0.0f;
        return ip[yi * W + xi];
    };
    float v = g(y0, x0) * (1.0f - wx) * (1.0f - wy)
            + g(y0, x0 + 1) * wx * (1.0f - wy)
            + g(y0 + 1, x0) * (1.0f - wx) * wy
            + g(y0 + 1, x0 + 1) * wx * wy;
    out[idx] = v;
}

// ---------------- correlation (7x7 disp) + lrelu ----------------
__global__ void corr_lrelu(const float* __restrict__ f1, const float* __restrict__ wp,
                           float* __restrict__ out, int C) {
    const int H = 12, W = 24, HW = 288;
    int idx = blockIdx.x * blockDim.x + threadIdx.x;
    int total = 4 * 49 * HW;
    if (idx >= total) return;
    int w = idx % W;
    int h = (idx / W) % H;
    int d = (idx / HW) % 49;
    int b = idx / (49 * HW);
    int di = d / 7 - 3;
    int dj = d % 7 - 3;
    int h2 = h + di;
    int w2 = w + dj;

    float s = 0.0f;
    if (h2 >= 0 && h2 < H && w2 >= 0 && w2 < W) {
        const float* a = f1 + (size_t)b * C * HW + h * W + w;
        const float* p = wp + (size_t)b * C * HW + h2 * W + w2;
        for (int c = 0; c < C; ++c) s = fmaf(a[(size_t)c * HW], p[(size_t)c * HW], s);
    }
    s /= (float)C;
    s = (s >= 0.0f) ? s : NEG_SLOPE * s;
    out[idx] = s;
}

// ---------------- host ----------------
extern "C" void kernel_launch(void* const* d_in, const int* in_sizes, int n_in,
                              void* d_out, int out_size, void* d_ws, size_t ws_size,
                              hipStream_t stream) {
    const float* img1 = (const float*)d_in[0];
    const float* img2 = (const float*)d_in[1];
    const float* flow = (const float*)d_in[2];
    float* out = (float*)d_out;

    const float* W[10];
    const float* Bs[10];
    for (int l = 0; l < 10; ++l) {
        W[l]  = (const float*)d_in[3 + 2 * l];
        Bs[l] = (const float*)d_in[4 + 2 * l];
    }

    // ws layout identical to proven footprint (47.85M floats = 191.4 MB)
    float* ws = (float*)d_ws;
    size_t off = 0;
    float* bufA = ws + off; off += 37748736;  // 4*32*384*768
    float* bufB = ws + off; off += 9437184;   // 4*32*192*384
    float* f1   = ws + off; off += 221184;    // 4*192*12*24
    float* f2   = ws + off; off += 221184;
    float* wrp  = ws + off; off += 221184;

    auto chain = [&](const float* img, float* fout) {
        // L1: 3->32, 7x7 s1 p3, 384x768 (kh-outer, no spill — R6 measured win)
        conv7x7<32, 384, 768>
            <<<dim3(cdiv(384*(768/4),256),1,4*(32/8)), 256, 0, stream>>>(img,  W[0], Bs[0], bufA);
        // L2: 32->32, 3x3 s2 p1 -> 192x384
        conv_blk<3,2,1, 32, 32, 384,768, 192,384, 8,4>
            <<<dim3(cdiv(192*(384/4),256),1,4*(32/8)), 256, 0, stream>>>(bufA, W[1], Bs[1], bufB);
        // L3: 32->32, s1
        conv_blk<3,1,1, 32, 32, 192,384, 192,384, 8,4>
            <<<dim3(cdiv(192*(384/4),256),1,4*(32/8)), 256, 0, stream>>>(bufB, W[2], Bs[2], bufA);
        // L4: 32->32, s1
        conv_blk<3,1,1, 32, 32, 192,384, 192,384, 8,4>
            <<<dim3(cdiv(192*(384/4),256),1,4*(32/8)), 256, 0, stream>>>(bufA, W[3], Bs[3], bufB);
        // L5: 32->64, s2 -> 96x192
        conv_blk<3,2,1, 32, 64, 192,384,  96,192, 8,4>
            <<<dim3(cdiv(96*(192/4),256),1,4*(64/8)), 256, 0, stream>>>(bufB, W[4], Bs[4], bufA);
        // L6: 64->64, s1
        conv_blk<3,1,1, 64, 64,  96,192,  96,192, 8,4>
            <<<dim3(cdiv(96*(192/4),256),1,4*(64/8)), 256, 0, stream>>>(bufA, W[5], Bs[5], bufB);
        // L7: 64->96, s2 -> 48x96
        conv_blk<3,2,1, 64, 96,  96,192,  48, 96, 8,4>
            <<<dim3(cdiv(48*(96/4),256),1,4*(96/8)), 256, 0, stream>>>(bufB, W[6], Bs[6], bufA);
        // L8: 96->96, s1
        conv_blk<3,1,1, 96, 96,  48, 96,  48, 96, 8,4>
            <<<dim3(cdiv(48*(96/4),256),1,4*(96/8)), 256, 0, stream>>>(bufA, W[7], Bs[7], bufB);
        // L9: 96->128, s2 -> 24x48
        conv_blk<3,2,1, 96,128,  48, 96,  24, 48, 8,4>
            <<<dim3(cdiv(24*(48/4),256),1,4*(128/8)), 256, 0, stream>>>(bufB, W[8], Bs[8], bufA);
        // L10: 128->192, s2 -> 12x24
        conv_blk<3,2,1,128,192,  24, 48,  12, 24, 8,4>
            <<<dim3(cdiv(12*(24/4),256),1,4*(192/8)), 256, 0, stream>>>(bufA, W[9], Bs[9], fout);
    };

    chain(img1, f1);
    chain(img2, f2);

    warp_kernel<<<cdiv(4 * 192 * 288, 256), 256, 0, stream>>>(f2, flow, wrp, 192);
    corr_lrelu<<<cdiv(4 * 49 * 288, 256), 256, 0, stream>>>(f1, wrp, out, 192);
}